// Round 1
// baseline (3659.611 us; speedup 1.0000x reference)
//
#include <hip/hip_runtime.h>
#include <math.h>

#define C 512
#define K 256
#define HW 160
#define NPIX (HW*HW)   // 25600
#define EPS 1e-5f

// ---------------- Kernel A: per-channel mean & max ----------------
__global__ void reduce_kernel(const float* __restrict__ x,
                              float* __restrict__ avg, float* __restrict__ mx) {
    int c = blockIdx.x;
    const float* xc = x + (size_t)c * NPIX;
    float s = 0.f, m = -INFINITY;
    for (int p = threadIdx.x; p < NPIX; p += 256) {
        float v = xc[p];
        s += v;
        m = fmaxf(m, v);
    }
    __shared__ float ss[256], sm[256];
    ss[threadIdx.x] = s; sm[threadIdx.x] = m;
    __syncthreads();
    for (int o = 128; o > 0; o >>= 1) {
        if (threadIdx.x < o) {
            ss[threadIdx.x] += ss[threadIdx.x + o];
            sm[threadIdx.x] = fmaxf(sm[threadIdx.x], sm[threadIdx.x + o]);
        }
        __syncthreads();
    }
    if (threadIdx.x == 0) {
        avg[c] = ss[0] / (float)NPIX;
        mx[c]  = sm[0];
    }
}

// ---------------- Kernel B: MLP + sigmoid + top-K selection ----------------
// one block, 512 threads
__global__ void mlp_select_kernel(const float* __restrict__ avg,
                                  const float* __restrict__ mx,
                                  const float* __restrict__ w_fc1,  // (256,512)
                                  const float* __restrict__ w_fc2,  // (512,256)
                                  float* __restrict__ scales_out,   // (512)
                                  int* __restrict__ idx,            // (256)
                                  int* __restrict__ pos) {          // (512)
    __shared__ float s_avg[C], s_mx[C], s_h[K], s_scales[C];
    __shared__ int s_sel[C];
    int t = threadIdx.x;
    s_avg[t] = avg[t];
    s_mx[t]  = mx[t];
    __syncthreads();
    if (t < K) {
        float ha = 0.f, hm = 0.f;
        const float* wr = w_fc1 + (size_t)t * C;
        for (int c = 0; c < C; c++) {
            float w = wr[c];
            ha += s_avg[c] * w;
            hm += s_mx[c] * w;
        }
        s_h[t] = fmaxf(ha, 0.f) + fmaxf(hm, 0.f);
    }
    __syncthreads();
    {
        float o = 0.f;
        const float* wr = w_fc2 + (size_t)t * K;
        for (int k = 0; k < K; k++) o += s_h[k] * wr[k];
        float sc = 1.f / (1.f + expf(-o));
        s_scales[t] = sc;
        scales_out[t] = sc;
    }
    __syncthreads();
    {
        float v = s_scales[t];
        int rank = 0;
        for (int i = 0; i < C; i++) {
            float u = s_scales[i];
            rank += (u > v) || (u == v && i < t);
        }
        s_sel[t] = (rank < K) ? 1 : 0;
    }
    __syncthreads();
    {
        int p = 0;
        for (int i = 0; i < t; i++) p += s_sel[i];
        if (s_sel[t]) { idx[p] = t; pos[t] = p; }
        else pos[t] = -1;
    }
}

// ---------------- Kernel C: combined 1x1 weight wA ----------------
// wA[co][c] = w_dc1[co][c]*scales[c] + (sel(c) ? w_dc1[co][512+pos(c)] : 0)
__global__ void wa_kernel(const float* __restrict__ w_dc1,
                          const float* __restrict__ scales,
                          const int* __restrict__ pos,
                          float* __restrict__ wA) {
    int co = blockIdx.x;
    int c  = threadIdx.x; // 512 threads
    const float* wr = w_dc1 + (size_t)co * 1024;
    float v = wr[c] * scales[c];
    int pp = pos[c];
    if (pp >= 0) v += wr[512 + pp];
    wA[(size_t)co * C + c] = v;
}

// ---------------- Kernel D: depthwise 3x3 + BN1 + ReLU -> x2 ----------------
__global__ void dw_kernel(const float* __restrict__ x,
                          const int* __restrict__ idx,
                          const float* __restrict__ wch,   // (256,9)
                          const float* __restrict__ g1,
                          const float* __restrict__ b1,
                          const float* __restrict__ m1,
                          const float* __restrict__ v1,
                          float* __restrict__ x2) {
    int k = blockIdx.y;
    int p = blockIdx.x * 256 + threadIdx.x;
    int c = idx[k];
    int y = p / HW, xx = p % HW;
    const float* xc = x + (size_t)c * NPIX;
    const float* wk = wch + k * 9;
    float acc = 0.f;
#pragma unroll
    for (int dy = 0; dy < 3; dy++) {
        int yy = y + dy - 1;
        if (yy < 0 || yy >= HW) continue;
#pragma unroll
        for (int dx = 0; dx < 3; dx++) {
            int xv = xx + dx - 1;
            if (xv < 0 || xv >= HW) continue;
            acc += xc[yy * HW + xv] * wk[dy * 3 + dx];
        }
    }
    float s = g1[k] * rsqrtf(v1[k] + EPS);
    float t = (acc - m1[k]) * s + b1[k];
    x2[(size_t)k * NPIX + p] = fmaxf(t, 0.f);
}

// ---------------- Kernel E: 1x1 conv (768 eff. channels) + bias + BN2 -> h ----
__global__ void conv1_kernel(const float* __restrict__ x,
                             const float* __restrict__ x2,
                             const float* __restrict__ wA,     // (512,512)
                             const float* __restrict__ w_dc1,  // (512,1024)
                             const float* __restrict__ b1,
                             const float* __restrict__ g2,
                             const float* __restrict__ b2,
                             const float* __restrict__ m2,
                             const float* __restrict__ v2,
                             float* __restrict__ h) {
    int p   = blockIdx.x * 256 + threadIdx.x;
    int co0 = blockIdx.y * 8;
    float acc[8] = {0.f,0.f,0.f,0.f,0.f,0.f,0.f,0.f};
    for (int c = 0; c < C; c++) {
        float xv = x[(size_t)c * NPIX + p];
#pragma unroll
        for (int u = 0; u < 8; u++)
            acc[u] += xv * wA[(size_t)(co0 + u) * C + c];
    }
    for (int k = 0; k < K; k++) {
        float xv = x2[(size_t)k * NPIX + p];
#pragma unroll
        for (int u = 0; u < 8; u++)
            acc[u] += xv * w_dc1[(size_t)(co0 + u) * 1024 + 768 + k];
    }
#pragma unroll
    for (int u = 0; u < 8; u++) {
        int co = co0 + u;
        float s = g2[co] * rsqrtf(v2[co] + EPS);
        float cc = (b1[co] - m2[co]) * s + b2[co];
        h[(size_t)co * NPIX + p] = acc[u] * s + cc;
    }
}

// ---------------- Kernel F: 3x3 conv + bias + ReLU -> out ----------------
__global__ void conv3_kernel(const float* __restrict__ h,
                             const float* __restrict__ w_dc2,  // (512,512,9)
                             const float* __restrict__ b_dc2,
                             float* __restrict__ out) {
    int p   = blockIdx.x * 256 + threadIdx.x;
    int co0 = blockIdx.y * 8;
    int y = p / HW, xx = p % HW;
    int off[9];
    bool ok[9];
#pragma unroll
    for (int t = 0; t < 9; t++) {
        int dy = t / 3 - 1, dx = t % 3 - 1;
        int yy = y + dy, xv = xx + dx;
        ok[t]  = (yy >= 0 && yy < HW && xv >= 0 && xv < HW);
        off[t] = yy * HW + xv;
    }
    float acc[8] = {0.f,0.f,0.f,0.f,0.f,0.f,0.f,0.f};
    for (int ci = 0; ci < C; ci++) {
        const float* hc = h + (size_t)ci * NPIX;
        float xv[9];
#pragma unroll
        for (int t = 0; t < 9; t++) xv[t] = ok[t] ? hc[off[t]] : 0.f;
#pragma unroll
        for (int t = 0; t < 9; t++) {
#pragma unroll
            for (int u = 0; u < 8; u++)
                acc[u] += xv[t] * w_dc2[((size_t)(co0 + u) * C + ci) * 9 + t];
        }
    }
#pragma unroll
    for (int u = 0; u < 8; u++) {
        out[(size_t)(co0 + u) * NPIX + p] = fmaxf(acc[u] + b_dc2[co0 + u], 0.f);
    }
}

extern "C" void kernel_launch(void* const* d_in, const int* in_sizes, int n_in,
                              void* d_out, int out_size, void* d_ws, size_t ws_size,
                              hipStream_t stream) {
    const float* x      = (const float*)d_in[0];
    const float* w_fc1  = (const float*)d_in[1];
    const float* w_fc2  = (const float*)d_in[2];
    const float* w_ch   = (const float*)d_in[3];
    const float* bn1_g  = (const float*)d_in[4];
    const float* bn1_b  = (const float*)d_in[5];
    const float* bn1_m  = (const float*)d_in[6];
    const float* bn1_v  = (const float*)d_in[7];
    const float* w_dc1  = (const float*)d_in[8];
    const float* b_dc1  = (const float*)d_in[9];
    const float* bn2_g  = (const float*)d_in[10];
    const float* bn2_b  = (const float*)d_in[11];
    const float* bn2_m  = (const float*)d_in[12];
    const float* bn2_v  = (const float*)d_in[13];
    const float* w_dc2  = (const float*)d_in[14];
    const float* b_dc2  = (const float*)d_in[15];
    float* out = (float*)d_out;

    // ---- workspace layout (bytes) ----
    char* ws = (char*)d_ws;
    float* avg    = (float*)(ws + 0);            // 512 f
    float* mx     = (float*)(ws + 2048);         // 512 f
    float* scales = (float*)(ws + 4096);         // 512 f
    int*   idx    = (int*)  (ws + 6144);         // 256 i
    int*   pos    = (int*)  (ws + 7168);         // 512 i
    float* wA     = (float*)(ws + 16384);        // 512*512 f = 1 MB
    float* x2     = (float*)(ws + (size_t)2097152);          // 256*25600 f = 26.2 MB
    float* h      = (float*)(ws + (size_t)2097152 + 26214400); // 512*25600 f = 52.4 MB

    reduce_kernel<<<C, 256, 0, stream>>>(x, avg, mx);
    mlp_select_kernel<<<1, C, 0, stream>>>(avg, mx, w_fc1, w_fc2, scales, idx, pos);
    wa_kernel<<<C, C, 0, stream>>>(w_dc1, scales, pos, wA);
    dw_kernel<<<dim3(NPIX / 256, K), 256, 0, stream>>>(x, idx, w_ch, bn1_g, bn1_b, bn1_m, bn1_v, x2);
    conv1_kernel<<<dim3(NPIX / 256, C / 8), 256, 0, stream>>>(x, x2, wA, w_dc1, b_dc1,
                                                              bn2_g, bn2_b, bn2_m, bn2_v, h);
    conv3_kernel<<<dim3(NPIX / 256, C / 8), 256, 0, stream>>>(h, w_dc2, b_dc2, out);
}

// Round 2
// 650.548 us; speedup vs baseline: 5.6254x; 5.6254x over previous
//
#include <hip/hip_runtime.h>
#include <math.h>

#define C 512
#define K 256
#define HW 160
#define NPIX (HW*HW)   // 25600
#define PW 162
#define EPS 1e-5f

typedef __attribute__((ext_vector_type(8))) short s16x8;
typedef __attribute__((ext_vector_type(4))) float f32x4;

__device__ __forceinline__ unsigned short f2bf(float f) {
    unsigned int u = __float_as_uint(f);
    u += 0x7fffu + ((u >> 16) & 1u);
    return (unsigned short)(u >> 16);
}

// ---------------- per-channel mean & max ----------------
__global__ void reduce_kernel(const float* __restrict__ x,
                              float* __restrict__ avg, float* __restrict__ mx) {
    int c = blockIdx.x;
    const float* xc = x + (size_t)c * NPIX;
    float s = 0.f, m = -INFINITY;
    for (int p = threadIdx.x; p < NPIX; p += 256) {
        float v = xc[p];
        s += v;
        m = fmaxf(m, v);
    }
    __shared__ float ss[256], sm[256];
    ss[threadIdx.x] = s; sm[threadIdx.x] = m;
    __syncthreads();
    for (int o = 128; o > 0; o >>= 1) {
        if (threadIdx.x < o) {
            ss[threadIdx.x] += ss[threadIdx.x + o];
            sm[threadIdx.x] = fmaxf(sm[threadIdx.x], sm[threadIdx.x + o]);
        }
        __syncthreads();
    }
    if (threadIdx.x == 0) {
        avg[c] = ss[0] / (float)NPIX;
        mx[c]  = sm[0];
    }
}

// ---------------- MLP + sigmoid + top-K selection ----------------
__global__ void mlp_select_kernel(const float* __restrict__ avg,
                                  const float* __restrict__ mx,
                                  const float* __restrict__ w_fc1,
                                  const float* __restrict__ w_fc2,
                                  float* __restrict__ scales_out,
                                  int* __restrict__ idx,
                                  int* __restrict__ pos) {
    __shared__ float s_avg[C], s_mx[C], s_h[K], s_scales[C];
    __shared__ int s_sel[C];
    int t = threadIdx.x;
    s_avg[t] = avg[t];
    s_mx[t]  = mx[t];
    __syncthreads();
    if (t < K) {
        float ha = 0.f, hm = 0.f;
        const float* wr = w_fc1 + (size_t)t * C;
        for (int c = 0; c < C; c++) {
            float w = wr[c];
            ha += s_avg[c] * w;
            hm += s_mx[c] * w;
        }
        s_h[t] = fmaxf(ha, 0.f) + fmaxf(hm, 0.f);
    }
    __syncthreads();
    {
        float o = 0.f;
        const float* wr = w_fc2 + (size_t)t * K;
        for (int k = 0; k < K; k++) o += s_h[k] * wr[k];
        float sc = 1.f / (1.f + expf(-o));
        s_scales[t] = sc;
        scales_out[t] = sc;
    }
    __syncthreads();
    {
        float v = s_scales[t];
        int rank = 0;
        for (int i = 0; i < C; i++) {
            float u = s_scales[i];
            rank += (u > v) || (u == v && i < t);
        }
        s_sel[t] = (rank < K) ? 1 : 0;
    }
    __syncthreads();
    {
        int p = 0;
        for (int i = 0; i < t; i++) p += s_sel[i];
        if (s_sel[t]) { idx[p] = t; pos[t] = p; }
        else pos[t] = -1;
    }
}

// ---------------- per-co affine for BN2 + bias fold ----------------
__global__ void affine_kernel(const float* __restrict__ b_dc1,
                              const float* __restrict__ g2, const float* __restrict__ b2,
                              const float* __restrict__ m2, const float* __restrict__ v2,
                              float* __restrict__ scale2, float* __restrict__ shift2) {
    int c = threadIdx.x;
    float s = g2[c] * rsqrtf(v2[c] + EPS);
    scale2[c] = s;
    shift2[c] = (b_dc1[c] - m2[c]) * s + b2[c];
}

// ---------------- combined 1x1 weight (768 eff. K) in bf16 ----------------
__global__ void wa_bf16_kernel(const float* __restrict__ w_dc1,
                               const float* __restrict__ scales,
                               const int* __restrict__ pos,
                               unsigned short* __restrict__ wA) {
    int co = blockIdx.x;
    const float* wr = w_dc1 + (size_t)co * 1024;
    for (int c = threadIdx.x; c < 768; c += 256) {
        float v;
        if (c < 512) {
            v = wr[c] * scales[c];
            int pp = pos[c];
            if (pp >= 0) v += wr[512 + pp];
        } else {
            v = wr[768 + (c - 512)];
        }
        wA[(size_t)co * 768 + c] = f2bf(v);
    }
}

// ---------------- repack conv3 weights: [co][ci][t] -> [t][co][ci] bf16 ----
__global__ void w3_kernel(const float* __restrict__ w_dc2, unsigned short* __restrict__ w3) {
    int co = blockIdx.x, t = blockIdx.y;
    for (int ci = threadIdx.x; ci < 512; ci += 256) {
        w3[((size_t)t * 512 + co) * 512 + ci] = f2bf(w_dc2[((size_t)co * 512 + ci) * 9 + t]);
    }
}

// ---------------- depthwise 3x3 + BN1 + ReLU -> x2 (fp32) ----------------
__global__ void dw_kernel(const float* __restrict__ x,
                          const int* __restrict__ idx,
                          const float* __restrict__ wch,
                          const float* __restrict__ g1,
                          const float* __restrict__ b1,
                          const float* __restrict__ m1,
                          const float* __restrict__ v1,
                          float* __restrict__ x2) {
    int k = blockIdx.y;
    int p = blockIdx.x * 256 + threadIdx.x;
    int c = idx[k];
    int y = p / HW, xx = p % HW;
    const float* xc = x + (size_t)c * NPIX;
    const float* wk = wch + k * 9;
    float acc = 0.f;
#pragma unroll
    for (int dy = 0; dy < 3; dy++) {
        int yy = y + dy - 1;
        if (yy < 0 || yy >= HW) continue;
#pragma unroll
        for (int dx = 0; dx < 3; dx++) {
            int xv = xx + dx - 1;
            if (xv < 0 || xv >= HW) continue;
            acc += xc[yy * HW + xv] * wk[dy * 3 + dx];
        }
    }
    float s = g1[k] * rsqrtf(v1[k] + EPS);
    float t = (acc - m1[k]) * s + b1[k];
    x2[(size_t)k * NPIX + p] = fmaxf(t, 0.f);
}

// ---------------- transpose x (512ch) and x2 (256ch) -> xcat_t[px][768] bf16 ----
__global__ void transpose_kernel(const float* __restrict__ x, const float* __restrict__ x2,
                                 unsigned short* __restrict__ xcat) {
    __shared__ float tile[32][33];
    int tx = threadIdx.x & 31, ty = threadIdx.x >> 5;
    int pbase = blockIdx.x * 32, cbase = blockIdx.y * 32;
#pragma unroll
    for (int j = 0; j < 4; j++) {
        int c = cbase + ty + j * 8;
        float v = (c < 512) ? x[(size_t)c * NPIX + pbase + tx]
                            : x2[(size_t)(c - 512) * NPIX + pbase + tx];
        tile[ty + j * 8][tx] = v;
    }
    __syncthreads();
#pragma unroll
    for (int j = 0; j < 4; j++) {
        int p = pbase + ty + j * 8;
        xcat[(size_t)p * 768 + cbase + tx] = f2bf(tile[tx][ty + j * 8]);
    }
}

// ---------------- zero-fill padded h buffer ----------------
__global__ void zero_kernel(uint4* __restrict__ p) {
    p[(size_t)blockIdx.x * 256 + threadIdx.x] = make_uint4(0u, 0u, 0u, 0u);
}

// ---------------- conv1 (1x1, K=768) via MFMA -> hpad_t bf16 ----------------
__global__ __launch_bounds__(256) void conv1_mfma(const unsigned short* __restrict__ xcat,
        const unsigned short* __restrict__ wA,
        const float* __restrict__ scale2, const float* __restrict__ shift2,
        unsigned short* __restrict__ hpad) {
    __shared__ short Al[160 * 32];
    __shared__ short Bl[128 * 32];
    int y = blockIdx.x, co0 = blockIdx.y * 128;
    int tid = threadIdx.x, lane = tid & 63, wv = tid >> 6;
    int wm = wv & 1, wn = wv >> 1;
    int l15 = lane & 15, q = lane >> 4;
    f32x4 acc[5][4] = {};
    for (int k0 = 0; k0 < 768; k0 += 32) {
        __syncthreads();
        for (int c = tid; c < 640; c += 256) {
            int i = c >> 2, j = c & 3;
            *(uint4*)&Al[c * 8] = *(const uint4*)&xcat[(size_t)(y * HW + i) * 768 + k0 + j * 8];
        }
        {
            int c = tid;
            int n = c >> 2, j = c & 3;
            *(uint4*)&Bl[c * 8] = *(const uint4*)&wA[(size_t)(co0 + n) * 768 + k0 + j * 8];
            c += 256; n = c >> 2; j = c & 3;
            *(uint4*)&Bl[c * 8] = *(const uint4*)&wA[(size_t)(co0 + n) * 768 + k0 + j * 8];
        }
        __syncthreads();
        s16x8 af[5], bfr[4];
#pragma unroll
        for (int i = 0; i < 5; i++)
            af[i] = *(const s16x8*)&Al[(wm * 80 + i * 16 + l15) * 32 + q * 8];
#pragma unroll
        for (int j = 0; j < 4; j++)
            bfr[j] = *(const s16x8*)&Bl[(wn * 64 + j * 16 + l15) * 32 + q * 8];
#pragma unroll
        for (int i = 0; i < 5; i++)
#pragma unroll
            for (int j = 0; j < 4; j++)
                acc[i][j] = __builtin_amdgcn_mfma_f32_16x16x32_bf16(af[i], bfr[j], acc[i][j], 0, 0, 0);
    }
#pragma unroll
    for (int j = 0; j < 4; j++) {
        int n = co0 + wn * 64 + j * 16 + l15;
        float s = scale2[n], c0 = shift2[n];
#pragma unroll
        for (int i = 0; i < 5; i++) {
            int xb = wm * 80 + i * 16 + q * 4;
#pragma unroll
            for (int r = 0; r < 4; r++) {
                size_t pp = (size_t)(y + 1) * PW + (xb + r + 1);
                hpad[pp * 512 + n] = f2bf(acc[i][j][r] * s + c0);
            }
        }
    }
}

// ---------------- conv3 (3x3, K=4608) via MFMA -> out fp32 ----------------
__global__ __launch_bounds__(256) void conv3_mfma(const unsigned short* __restrict__ hpad,
        const unsigned short* __restrict__ w3,
        const float* __restrict__ bias, float* __restrict__ out) {
    __shared__ short Al[162 * 32];
    __shared__ short Bl[3 * 128 * 32];
    int y = blockIdx.x, co0 = blockIdx.y * 128;
    int tid = threadIdx.x, lane = tid & 63, wv = tid >> 6;
    int wm = wv & 1, wn = wv >> 1;
    int l15 = lane & 15, q = lane >> 4;
    f32x4 acc[5][4] = {};
    for (int dy = 0; dy < 3; dy++) {
        const unsigned short* w3d = w3 + (size_t)dy * 3 * 512 * 512;
        size_t arow = (size_t)(y + dy) * PW;   // padded row y+1+(dy-1)
        for (int kc = 0; kc < 512; kc += 32) {
            __syncthreads();
            for (int c = tid; c < 648; c += 256) {
                int i = c >> 2, j = c & 3;
                *(uint4*)&Al[c * 8] = *(const uint4*)&hpad[(arow + i) * 512 + kc + j * 8];
            }
            for (int c = tid; c < 1536; c += 256) {
                int tt = c >> 9, n = (c >> 2) & 127, j = c & 3;
                *(uint4*)&Bl[c * 8] = *(const uint4*)&w3d[((size_t)tt * 512 + co0 + n) * 512 + kc + j * 8];
            }
            __syncthreads();
#pragma unroll
            for (int dx = 0; dx < 3; dx++) {
                s16x8 af[5], bfr[4];
#pragma unroll
                for (int i = 0; i < 5; i++)
                    af[i] = *(const s16x8*)&Al[(wm * 80 + i * 16 + l15 + dx) * 32 + q * 8];
#pragma unroll
                for (int j = 0; j < 4; j++)
                    bfr[j] = *(const s16x8*)&Bl[dx * 4096 + (wn * 64 + j * 16 + l15) * 32 + q * 8];
#pragma unroll
                for (int i = 0; i < 5; i++)
#pragma unroll
                    for (int j = 0; j < 4; j++)
                        acc[i][j] = __builtin_amdgcn_mfma_f32_16x16x32_bf16(af[i], bfr[j], acc[i][j], 0, 0, 0);
            }
        }
    }
#pragma unroll
    for (int j = 0; j < 4; j++) {
        int n = co0 + wn * 64 + j * 16 + l15;
        float b = bias[n];
        float* op = out + (size_t)n * NPIX + y * HW;
#pragma unroll
        for (int i = 0; i < 5; i++) {
            int xb = wm * 80 + i * 16 + q * 4;
            float4 v;
            v.x = fmaxf(acc[i][j][0] + b, 0.f);
            v.y = fmaxf(acc[i][j][1] + b, 0.f);
            v.z = fmaxf(acc[i][j][2] + b, 0.f);
            v.w = fmaxf(acc[i][j][3] + b, 0.f);
            *(float4*)&op[xb] = v;
        }
    }
}

extern "C" void kernel_launch(void* const* d_in, const int* in_sizes, int n_in,
                              void* d_out, int out_size, void* d_ws, size_t ws_size,
                              hipStream_t stream) {
    const float* x      = (const float*)d_in[0];
    const float* w_fc1  = (const float*)d_in[1];
    const float* w_fc2  = (const float*)d_in[2];
    const float* w_ch   = (const float*)d_in[3];
    const float* bn1_g  = (const float*)d_in[4];
    const float* bn1_b  = (const float*)d_in[5];
    const float* bn1_m  = (const float*)d_in[6];
    const float* bn1_v  = (const float*)d_in[7];
    const float* w_dc1  = (const float*)d_in[8];
    const float* b_dc1  = (const float*)d_in[9];
    const float* bn2_g  = (const float*)d_in[10];
    const float* bn2_b  = (const float*)d_in[11];
    const float* bn2_m  = (const float*)d_in[12];
    const float* bn2_v  = (const float*)d_in[13];
    const float* w_dc2  = (const float*)d_in[14];
    const float* b_dc2  = (const float*)d_in[15];
    float* out = (float*)d_out;

    char* ws = (char*)d_ws;
    float* avg    = (float*)(ws + 0);
    float* mx     = (float*)(ws + 2048);
    float* scales = (float*)(ws + 4096);
    int*   idx    = (int*)  (ws + 6144);
    int*   pos    = (int*)  (ws + 7168);
    float* scale2 = (float*)(ws + 9216);
    float* shift2 = (float*)(ws + 11264);
    unsigned short* wA   = (unsigned short*)(ws + 16384);              // 512*768*2  = 786432
    unsigned short* w3   = (unsigned short*)(ws + 802816);             // 9*512*512*2 = 4718592
    float*          x2   = (float*)         (ws + 5521408);            // 256*25600*4 = 26214400
    unsigned short* xcat = (unsigned short*)(ws + 31735808);           // 25600*768*2 = 39321600
    unsigned short* hpad = (unsigned short*)(ws + 71057408);           // 162*162*512*2 = 26873856

    reduce_kernel<<<C, 256, 0, stream>>>(x, avg, mx);
    mlp_select_kernel<<<1, C, 0, stream>>>(avg, mx, w_fc1, w_fc2, scales, idx, pos);
    affine_kernel<<<1, C, 0, stream>>>(b_dc1, bn2_g, bn2_b, bn2_m, bn2_v, scale2, shift2);
    wa_bf16_kernel<<<C, 256, 0, stream>>>(w_dc1, scales, pos, wA);
    w3_kernel<<<dim3(C, 9), 256, 0, stream>>>(w_dc2, w3);
    zero_kernel<<<6561, 256, 0, stream>>>((uint4*)hpad);
    dw_kernel<<<dim3(NPIX / 256, K), 256, 0, stream>>>(x, idx, w_ch, bn1_g, bn1_b, bn1_m, bn1_v, x2);
    transpose_kernel<<<dim3(NPIX / 32, 24), 256, 0, stream>>>(x, x2, xcat);
    conv1_mfma<<<dim3(HW, 4), 256, 0, stream>>>(xcat, wA, scale2, shift2, hpad);
    conv3_mfma<<<dim3(HW, 4), 256, 0, stream>>>(hpad, w3, b_dc2, out);
}